// Round 4
// baseline (932.884 us; speedup 1.0000x reference)
//
#include <hip/hip_runtime.h>

// F0=64, F1=128, F2=64. Nodes bucketed by 128: NB = ceil(n/128) buckets.
// Pipeline: bucket_hist -> scan2 -> bucket_place -> src_deg -> scale ->
//           bucket_agg(layer1, computes norm_dst) -> gemm1 -> gemm2 ->
//           bucket_agg(layer2, +b2)

#define NBMAX 1024  // supports n up to 131072

__global__ __launch_bounds__(256) void bucket_hist(const int* __restrict__ src,
        const int* __restrict__ dst, int* __restrict__ gcnt_s, int* __restrict__ gcnt_d,
        int n_edges, int nb) {
    __shared__ int hs[NBMAX], hd[NBMAX];
    for (int i = threadIdx.x; i < nb; i += 256) { hs[i] = 0; hd[i] = 0; }
    __syncthreads();
    int chunk = (n_edges + gridDim.x - 1) / gridDim.x;
    int e0 = blockIdx.x * chunk;
    int e1 = e0 + chunk; if (e1 > n_edges) e1 = n_edges;
    for (int e = e0 + (int)threadIdx.x; e < e1; e += 256) {
        atomicAdd(&hs[src[e] >> 7], 1);
        atomicAdd(&hd[dst[e] >> 7], 1);
    }
    __syncthreads();
    for (int i = threadIdx.x; i < nb; i += 256) {
        if (hs[i]) atomicAdd(&gcnt_s[i], hs[i]);
        if (hd[i]) atomicAdd(&gcnt_d[i], hd[i]);
    }
}

// block 0 scans (c0->o0,u0), block 1 scans (c1->o1,u1). n <= 1024 per array
// handled in 1024-chunks (loop kept for generality).
__global__ __launch_bounds__(1024) void scan2(const int* __restrict__ c0,
        int* __restrict__ o0, int* __restrict__ u0,
        const int* __restrict__ c1, int* __restrict__ o1, int* __restrict__ u1, int n) {
    const int* cnt = blockIdx.x ? c1 : c0;
    int* offs = blockIdx.x ? o1 : o0;
    int* cur  = blockIdx.x ? u1 : u0;
    __shared__ int wsum[16];
    const int lane = threadIdx.x & 63;
    const int wid  = threadIdx.x >> 6;
    int carry = 0;
    for (int base = 0; base < n; base += 1024) {
        int i = base + (int)threadIdx.x;
        int v = (i < n) ? cnt[i] : 0;
        int incl = v;
        #pragma unroll
        for (int d = 1; d < 64; d <<= 1) {
            int t = __shfl_up(incl, d, 64);
            if (lane >= d) incl += t;
        }
        if (lane == 63) wsum[wid] = incl;
        __syncthreads();
        if (wid == 0) {
            int w = (lane < 16) ? wsum[lane] : 0;
            #pragma unroll
            for (int d = 1; d < 16; d <<= 1) {
                int t = __shfl_up(w, d, 64);
                if (lane >= d) w += t;
            }
            if (lane < 16) wsum[lane] = w;
        }
        __syncthreads();
        int wexcl = (wid == 0) ? 0 : wsum[wid - 1];
        int excl = carry + wexcl + (incl - v);
        if (i < n) { offs[i] = excl; cur[i] = excl; }
        int total = wsum[15];
        __syncthreads();
        carry += total;
    }
    if (threadIdx.x == 0) offs[n] = carry;
}

// Two-pass per-block placement: LDS hist -> one reservation atomic per
// (block,bucket) -> LDS-cursor scatter. dst entry: (dst&127)<<25 | src.
__global__ __launch_bounds__(256) void bucket_place(const int* __restrict__ src,
        const int* __restrict__ dst, int* __restrict__ cur_s, int* __restrict__ cur_d,
        unsigned char* __restrict__ ss, unsigned int* __restrict__ sd,
        int n_edges, int nb) {
    __shared__ int hs[NBMAX], hd[NBMAX], bs[NBMAX], bd[NBMAX];
    for (int i = threadIdx.x; i < nb; i += 256) { hs[i] = 0; hd[i] = 0; }
    __syncthreads();
    int chunk = (n_edges + gridDim.x - 1) / gridDim.x;
    int e0 = blockIdx.x * chunk;
    int e1 = e0 + chunk; if (e1 > n_edges) e1 = n_edges;
    for (int e = e0 + (int)threadIdx.x; e < e1; e += 256) {
        atomicAdd(&hs[src[e] >> 7], 1);
        atomicAdd(&hd[dst[e] >> 7], 1);
    }
    __syncthreads();
    for (int i = threadIdx.x; i < nb; i += 256) {
        int v = hs[i]; bs[i] = v ? atomicAdd(&cur_s[i], v) : 0; hs[i] = 0;
        v = hd[i];     bd[i] = v ? atomicAdd(&cur_d[i], v) : 0; hd[i] = 0;
    }
    __syncthreads();
    for (int e = e0 + (int)threadIdx.x; e < e1; e += 256) {
        int s = src[e], d = dst[e];
        int b1 = s >> 7, b2 = d >> 7;
        int ps = bs[b1] + atomicAdd(&hs[b1], 1);
        ss[ps] = (unsigned char)(s & 127);
        int pd = bd[b2] + atomicAdd(&hd[b2], 1);
        sd[pd] = ((unsigned int)(d & 127) << 25) | (unsigned int)s;
    }
}

// One block per src-bucket: count occurrences, write norm_src.
__global__ __launch_bounds__(256) void src_deg(const unsigned char* __restrict__ ss,
        const int* __restrict__ offs_s, float* __restrict__ norm_src, int n) {
    __shared__ int cnt[128];
    if (threadIdx.x < 128) cnt[threadIdx.x] = 0;
    __syncthreads();
    int b = blockIdx.x;
    int s0 = offs_s[b], s1 = offs_s[b + 1];
    for (int i = s0 + (int)threadIdx.x; i < s1; i += 256)
        atomicAdd(&cnt[ss[i]], 1);
    __syncthreads();
    if (threadIdx.x < 128) {
        int node = b * 128 + (int)threadIdx.x;
        if (node < n) {
            int c = cnt[threadIdx.x]; if (c < 1) c = 1;
            norm_src[node] = 1.0f / sqrtf((float)c);
        }
    }
}

__global__ void scale_kernel(const float4* __restrict__ h4, const float* __restrict__ norm,
                             float4* __restrict__ x4, int n4) {
    int idx = blockIdx.x * blockDim.x + threadIdx.x;
    if (idx < n4) {
        float s = norm[idx >> 4];
        float4 v = h4[idx];
        v.x *= s; v.y *= s; v.z *= s; v.w *= s;
        x4[idx] = v;
    }
}

// One block per dst-bucket. 128x64 f32 accumulator in LDS; waves stream the
// bucket's packed edges, gather x[src] rows (64-lane coalesced 256B), and
// ds_add into the accumulator. Layer 1 also counts in-degree -> norm_dst.
__global__ __launch_bounds__(256) void bucket_agg(const float* __restrict__ x,
        const unsigned int* __restrict__ sd, const int* __restrict__ offs_d,
        float* __restrict__ norm_dst, const float* __restrict__ bias,
        float* __restrict__ out, int n, int compute_norm) {
    __shared__ float acc[128 * 64];
    __shared__ unsigned int stage[256];
    __shared__ int cnt[128];
    __shared__ float nrm[128];
    for (int i = threadIdx.x; i < 128 * 64; i += 256) acc[i] = 0.0f;
    if (threadIdx.x < 128) cnt[threadIdx.x] = 0;
    __syncthreads();

    const int b = blockIdx.x;
    const int s0 = offs_d[b], s1 = offs_d[b + 1];
    const int lane = threadIdx.x & 63;
    const int w = threadIdx.x >> 6;

    for (int base = s0; base < s1; base += 256) {
        int i = base + (int)threadIdx.x;
        if (i < s1) stage[threadIdx.x] = sd[i];
        __syncthreads();
        int m = s1 - base; if (m > 256) m = 256;
        int lo = w * 64;
        int hi = lo + 64; if (hi > m) hi = m;
        for (int j = lo; j < hi; j += 8) {
            float v[8]; int dl[8];
            #pragma unroll
            for (int u = 0; u < 8; ++u) {
                int jj = j + u;
                bool ok = jj < hi;
                unsigned int e = stage[ok ? jj : lo];
                dl[u] = (int)(e >> 25);
                int s = (int)(e & 0x1FFFFFFu);
                float val = x[(size_t)s * 64 + lane];
                v[u] = ok ? val : 0.0f;
                if (compute_norm && lane == 0 && ok) atomicAdd(&cnt[dl[u]], 1);
            }
            #pragma unroll
            for (int u = 0; u < 8; ++u)
                atomicAdd(&acc[dl[u] * 64 + lane], v[u]);
        }
        __syncthreads();
    }

    if (threadIdx.x < 128) {
        int node = b * 128 + (int)threadIdx.x;
        float v = 1.0f;
        if (node < n) {
            if (compute_norm) {
                int c = cnt[threadIdx.x]; if (c < 1) c = 1;
                v = 1.0f / sqrtf((float)c);
                norm_dst[node] = v;
            } else {
                v = norm_dst[node];
            }
        }
        nrm[threadIdx.x] = v;
    }
    __syncthreads();

    for (int t = threadIdx.x; t < 128 * 16; t += 256) {
        int nl = t >> 4;
        int c4 = (t & 15) * 4;
        int node = b * 128 + nl;
        if (node >= n) break;
        float s = nrm[nl];
        float4 r = *(float4*)(acc + nl * 64 + c4);
        r.x *= s; r.y *= s; r.z *= s; r.w *= s;
        if (bias) {
            const float4 bb = *(const float4*)(bias + c4);
            r.x += bb.x; r.y += bb.y; r.z += bb.z; r.w += bb.w;
        }
        *(float4*)(out + (size_t)node * 64 + c4) = r;
    }
}

// H1[n,128] = relu(A[n,64] @ W1[64,128] + b1) * norm_src[node]
__global__ __launch_bounds__(256) void gemm1(const float* __restrict__ A,
        const float* __restrict__ W1, const float* __restrict__ b1,
        const float* __restrict__ norm, float* __restrict__ H1, int n_nodes) {
    __shared__ float Ws[64 * 128];
    __shared__ float As[64 * 68];
    __shared__ float b1s[128];
    const int tid = threadIdx.x;
    for (int idx = tid; idx < 64 * 128; idx += 256) Ws[idx] = W1[idx];
    if (tid < 128) b1s[tid] = b1[tid];

    const int m0 = blockIdx.x * 64;
    const float4* Ag = (const float4*)(A + (size_t)m0 * 64);
    #pragma unroll
    for (int i = 0; i < 4; ++i) {
        int idx = tid + i * 256;
        int m = idx >> 4;
        int k4 = (idx & 15) * 4;
        float4 v = make_float4(0.f, 0.f, 0.f, 0.f);
        if (m0 + m < n_nodes) v = Ag[idx];
        *(float4*)(As + m * 68 + k4) = v;
    }
    __syncthreads();

    const int tx = tid & 15;
    const int ty = tid >> 4;
    float acc[4][8];
    #pragma unroll
    for (int i = 0; i < 4; ++i)
        #pragma unroll
        for (int j = 0; j < 8; ++j) acc[i][j] = 0.0f;

    const float* Ap = As + ty * 4 * 68;
    const float* Wp = Ws + tx * 8;
    for (int k = 0; k < 64; ++k) {
        float a0 = Ap[k];
        float a1 = Ap[68 + k];
        float a2 = Ap[136 + k];
        float a3 = Ap[204 + k];
        float w[8];
        #pragma unroll
        for (int j = 0; j < 8; ++j) w[j] = Wp[k * 128 + j];
        #pragma unroll
        for (int j = 0; j < 8; ++j) {
            acc[0][j] = fmaf(a0, w[j], acc[0][j]);
            acc[1][j] = fmaf(a1, w[j], acc[1][j]);
            acc[2][j] = fmaf(a2, w[j], acc[2][j]);
            acc[3][j] = fmaf(a3, w[j], acc[3][j]);
        }
    }

    #pragma unroll
    for (int i = 0; i < 4; ++i) {
        int node = m0 + ty * 4 + i;
        if (node < n_nodes) {
            float s = norm[node];
            float r[8];
            #pragma unroll
            for (int j = 0; j < 8; ++j) {
                float v = acc[i][j] + b1s[tx * 8 + j];
                v = v > 0.0f ? v : 0.0f;
                r[j] = v * s;
            }
            float* o = H1 + (size_t)node * 128 + tx * 8;
            *(float4*)(o)     = make_float4(r[0], r[1], r[2], r[3]);
            *(float4*)(o + 4) = make_float4(r[4], r[5], r[6], r[7]);
        }
    }
}

// Y2[n,64] = H1[n,128] @ W2[128,64]
__global__ __launch_bounds__(256) void gemm2(const float* __restrict__ H1,
        const float* __restrict__ W2, float* __restrict__ Y2, int n_nodes) {
    __shared__ float Ws[128 * 64];
    __shared__ float Hs[64 * 132];
    const int tid = threadIdx.x;
    for (int idx = tid; idx < 128 * 64; idx += 256) Ws[idx] = W2[idx];

    const int m0 = blockIdx.x * 64;
    const float4* Hg = (const float4*)(H1 + (size_t)m0 * 128);
    #pragma unroll
    for (int i = 0; i < 8; ++i) {
        int idx = tid + i * 256;
        int m = idx >> 5;
        int k4 = (idx & 31) * 4;
        float4 v = make_float4(0.f, 0.f, 0.f, 0.f);
        if (m0 + m < n_nodes) v = Hg[idx];
        *(float4*)(Hs + m * 132 + k4) = v;
    }
    __syncthreads();

    const int tx = tid & 15;
    const int ty = tid >> 4;
    float acc[4][4];
    #pragma unroll
    for (int i = 0; i < 4; ++i)
        #pragma unroll
        for (int j = 0; j < 4; ++j) acc[i][j] = 0.0f;

    const float* Ap = Hs + ty * 4 * 132;
    for (int k = 0; k < 128; ++k) {
        float a0 = Ap[k];
        float a1 = Ap[132 + k];
        float a2 = Ap[264 + k];
        float a3 = Ap[396 + k];
        const float4 w = *(const float4*)(Ws + k * 64 + tx * 4);
        acc[0][0] = fmaf(a0, w.x, acc[0][0]); acc[0][1] = fmaf(a0, w.y, acc[0][1]);
        acc[0][2] = fmaf(a0, w.z, acc[0][2]); acc[0][3] = fmaf(a0, w.w, acc[0][3]);
        acc[1][0] = fmaf(a1, w.x, acc[1][0]); acc[1][1] = fmaf(a1, w.y, acc[1][1]);
        acc[1][2] = fmaf(a1, w.z, acc[1][2]); acc[1][3] = fmaf(a1, w.w, acc[1][3]);
        acc[2][0] = fmaf(a2, w.x, acc[2][0]); acc[2][1] = fmaf(a2, w.y, acc[2][1]);
        acc[2][2] = fmaf(a2, w.z, acc[2][2]); acc[2][3] = fmaf(a2, w.w, acc[2][3]);
        acc[3][0] = fmaf(a3, w.x, acc[3][0]); acc[3][1] = fmaf(a3, w.y, acc[3][1]);
        acc[3][2] = fmaf(a3, w.z, acc[3][2]); acc[3][3] = fmaf(a3, w.w, acc[3][3]);
    }

    #pragma unroll
    for (int i = 0; i < 4; ++i) {
        int node = m0 + ty * 4 + i;
        if (node < n_nodes) {
            *(float4*)(Y2 + (size_t)node * 64 + tx * 4) =
                make_float4(acc[i][0], acc[i][1], acc[i][2], acc[i][3]);
        }
    }
}

extern "C" void kernel_launch(void* const* d_in, const int* in_sizes, int n_in,
                              void* d_out, int out_size, void* d_ws, size_t ws_size,
                              hipStream_t stream) {
    const float* h   = (const float*)d_in[0];
    const int*   src = (const int*)d_in[1];
    const int*   dst = (const int*)d_in[2];
    const float* W1  = (const float*)d_in[3];
    const float* b1  = (const float*)d_in[4];
    const float* W2  = (const float*)d_in[5];
    const float* b2  = (const float*)d_in[6];
    float* out = (float*)d_out;

    const int n_nodes = in_sizes[0] / 64;
    const int n_edges = in_sizes[1];
    const int nb = (n_nodes + 127) >> 7;

    float* ws = (float*)d_ws;
    float* x        = ws;                            // [n,64]; y2 alias
    float* agg1     = x + (size_t)n_nodes * 64;      // [n,64]
    float* H1       = agg1 + (size_t)n_nodes * 64;   // [n,128]
    float* norm_src = H1 + (size_t)n_nodes * 128;    // [n]
    float* norm_dst = norm_src + n_nodes;            // [n]
    int* gcnt_s = (int*)(norm_dst + n_nodes);        // [nb]
    int* gcnt_d = gcnt_s + nb;                       // [nb]
    int* offs_s = gcnt_d + nb;                       // [nb+1]
    int* offs_d = offs_s + nb + 1;                   // [nb+1]
    int* cur_s  = offs_d + nb + 1;                   // [nb]
    int* cur_d  = cur_s + nb;                        // [nb]
    unsigned int* stream_d = (unsigned int*)(cur_d + nb);   // [E]
    unsigned char* stream_s = (unsigned char*)(stream_d + n_edges); // [E]
    float* y2 = x;

    hipMemsetAsync(gcnt_s, 0, 2 * (size_t)nb * sizeof(int), stream);

    bucket_hist<<<128, 256, 0, stream>>>(src, dst, gcnt_s, gcnt_d, n_edges, nb);
    scan2<<<2, 1024, 0, stream>>>(gcnt_s, offs_s, cur_s, gcnt_d, offs_d, cur_d, nb);
    bucket_place<<<128, 256, 0, stream>>>(src, dst, cur_s, cur_d, stream_s, stream_d,
                                          n_edges, nb);
    src_deg<<<nb, 256, 0, stream>>>(stream_s, offs_s, norm_src, n_nodes);

    int n4 = n_nodes * 16;
    scale_kernel<<<(n4 + 255) / 256, 256, 0, stream>>>((const float4*)h, norm_src,
                                                       (float4*)x, n4);

    bucket_agg<<<nb, 256, 0, stream>>>(x, stream_d, offs_d, norm_dst, nullptr,
                                       agg1, n_nodes, 1);

    int tb = (n_nodes + 63) / 64;
    gemm1<<<tb, 256, 0, stream>>>(agg1, W1, b1, norm_src, H1, n_nodes);
    gemm2<<<tb, 256, 0, stream>>>(H1, W2, y2, n_nodes);

    bucket_agg<<<nb, 256, 0, stream>>>(y2, stream_d, offs_d, norm_dst, b2,
                                       out, n_nodes, 0);
}

// Round 5
// 246.228 us; speedup vs baseline: 3.7887x; 3.7887x over previous
//
#include <hip/hip_runtime.h>

// F0=64, F1=128, F2=64. Two-level CSR build (buckets of 128 nodes, LDS
// histograms, no per-node global atomics) + one-wave-per-node register gather.
// Pipeline: bucket_hist -> scan2 -> bucket_place -> src_deg -> bucket_sort ->
//           gather1(h, per-edge norm_src fold) -> gemm1 -> gemm2 -> gather2(+b2)

#define NBMAX 1024  // supports n up to 131072

__global__ __launch_bounds__(256) void bucket_hist(const int* __restrict__ src,
        const int* __restrict__ dst, int* __restrict__ gcnt_s, int* __restrict__ gcnt_d,
        int n_edges, int nb) {
    __shared__ int hs[NBMAX], hd[NBMAX];
    for (int i = threadIdx.x; i < nb; i += 256) { hs[i] = 0; hd[i] = 0; }
    __syncthreads();
    int chunk = (n_edges + gridDim.x - 1) / gridDim.x;
    int e0 = blockIdx.x * chunk;
    int e1 = e0 + chunk; if (e1 > n_edges) e1 = n_edges;
    for (int e = e0 + (int)threadIdx.x; e < e1; e += 256) {
        atomicAdd(&hs[src[e] >> 7], 1);
        atomicAdd(&hd[dst[e] >> 7], 1);
    }
    __syncthreads();
    for (int i = threadIdx.x; i < nb; i += 256) {
        if (hs[i]) atomicAdd(&gcnt_s[i], hs[i]);
        if (hd[i]) atomicAdd(&gcnt_d[i], hd[i]);
    }
}

// block 0 scans (c0->o0,u0), block 1 scans (c1->o1,u1).
__global__ __launch_bounds__(1024) void scan2(const int* __restrict__ c0,
        int* __restrict__ o0, int* __restrict__ u0,
        const int* __restrict__ c1, int* __restrict__ o1, int* __restrict__ u1, int n) {
    const int* cnt = blockIdx.x ? c1 : c0;
    int* offs = blockIdx.x ? o1 : o0;
    int* cur  = blockIdx.x ? u1 : u0;
    __shared__ int wsum[16];
    const int lane = threadIdx.x & 63;
    const int wid  = threadIdx.x >> 6;
    int carry = 0;
    for (int base = 0; base < n; base += 1024) {
        int i = base + (int)threadIdx.x;
        int v = (i < n) ? cnt[i] : 0;
        int incl = v;
        #pragma unroll
        for (int d = 1; d < 64; d <<= 1) {
            int t = __shfl_up(incl, d, 64);
            if (lane >= d) incl += t;
        }
        if (lane == 63) wsum[wid] = incl;
        __syncthreads();
        if (wid == 0) {
            int w = (lane < 16) ? wsum[lane] : 0;
            #pragma unroll
            for (int d = 1; d < 16; d <<= 1) {
                int t = __shfl_up(w, d, 64);
                if (lane >= d) w += t;
            }
            if (lane < 16) wsum[lane] = w;
        }
        __syncthreads();
        int wexcl = (wid == 0) ? 0 : wsum[wid - 1];
        int excl = carry + wexcl + (incl - v);
        if (i < n) { offs[i] = excl; cur[i] = excl; }
        int total = wsum[15];
        __syncthreads();
        carry += total;
    }
    if (threadIdx.x == 0) offs[n] = carry;
}

// Per-block LDS hist -> one reservation atomic per (block,bucket) -> LDS-cursor
// scatter. dst entry: (dst&127)<<25 | src. src entry: 1 byte local id.
__global__ __launch_bounds__(256) void bucket_place(const int* __restrict__ src,
        const int* __restrict__ dst, int* __restrict__ cur_s, int* __restrict__ cur_d,
        unsigned char* __restrict__ ss, unsigned int* __restrict__ sd,
        int n_edges, int nb) {
    __shared__ int hs[NBMAX], hd[NBMAX], bs[NBMAX], bd[NBMAX];
    for (int i = threadIdx.x; i < nb; i += 256) { hs[i] = 0; hd[i] = 0; }
    __syncthreads();
    int chunk = (n_edges + gridDim.x - 1) / gridDim.x;
    int e0 = blockIdx.x * chunk;
    int e1 = e0 + chunk; if (e1 > n_edges) e1 = n_edges;
    for (int e = e0 + (int)threadIdx.x; e < e1; e += 256) {
        atomicAdd(&hs[src[e] >> 7], 1);
        atomicAdd(&hd[dst[e] >> 7], 1);
    }
    __syncthreads();
    for (int i = threadIdx.x; i < nb; i += 256) {
        int v = hs[i]; bs[i] = v ? atomicAdd(&cur_s[i], v) : 0; hs[i] = 0;
        v = hd[i];     bd[i] = v ? atomicAdd(&cur_d[i], v) : 0; hd[i] = 0;
    }
    __syncthreads();
    for (int e = e0 + (int)threadIdx.x; e < e1; e += 256) {
        int s = src[e], d = dst[e];
        int b1 = s >> 7, b2 = d >> 7;
        int ps = bs[b1] + atomicAdd(&hs[b1], 1);
        ss[ps] = (unsigned char)(s & 127);
        int pd = bd[b2] + atomicAdd(&hd[b2], 1);
        sd[pd] = ((unsigned int)(d & 127) << 25) | (unsigned int)s;
    }
}

// One block per src-bucket: count occurrences -> norm_src.
__global__ __launch_bounds__(256) void src_deg(const unsigned char* __restrict__ ss,
        const int* __restrict__ offs_s, float* __restrict__ norm_src, int n) {
    __shared__ int cnt[128];
    if (threadIdx.x < 128) cnt[threadIdx.x] = 0;
    __syncthreads();
    int b = blockIdx.x;
    int s0 = offs_s[b], s1 = offs_s[b + 1];
    for (int i = s0 + (int)threadIdx.x; i < s1; i += 256)
        atomicAdd(&cnt[ss[i]], 1);
    __syncthreads();
    if (threadIdx.x < 128) {
        int node = b * 128 + (int)threadIdx.x;
        if (node < n) {
            int c = cnt[threadIdx.x]; if (c < 1) c = 1;
            norm_src[node] = 1.0f / sqrtf((float)c);
        }
    }
}

// One block per dst-bucket: LDS 128-bin count -> scan -> per-node CSR offsets
// (globally consistent since buckets are contiguous) + LDS-cursor placement
// of full src ids. Also writes norm_dst.
__global__ __launch_bounds__(256) void bucket_sort(const unsigned int* __restrict__ sd,
        const int* __restrict__ offs_d, int* __restrict__ node_offs,
        int* __restrict__ src_sorted, float* __restrict__ norm_dst, int n, int nb) {
    __shared__ int cnt[128], cur[128];
    __shared__ int w0tot;
    const int b = blockIdx.x;
    const int s0 = offs_d[b], s1 = offs_d[b + 1];
    if (threadIdx.x < 128) cnt[threadIdx.x] = 0;
    __syncthreads();
    for (int i = s0 + (int)threadIdx.x; i < s1; i += 256)
        atomicAdd(&cnt[sd[i] >> 25], 1);
    __syncthreads();
    const int lane = threadIdx.x & 63;
    const int wid  = threadIdx.x >> 6;
    int v = (threadIdx.x < 128) ? cnt[threadIdx.x] : 0;
    int incl = v;
    #pragma unroll
    for (int d = 1; d < 64; d <<= 1) {
        int t = __shfl_up(incl, d, 64);
        if (lane >= d) incl += t;
    }
    if (threadIdx.x == 63) w0tot = incl;
    __syncthreads();
    if (threadIdx.x < 128) {
        int excl = incl - v + (wid == 1 ? w0tot : 0);
        cur[threadIdx.x] = excl;
        int node = b * 128 + (int)threadIdx.x;
        if (node < n) {
            node_offs[node] = s0 + excl;
            int c = v; if (c < 1) c = 1;
            norm_dst[node] = 1.0f / sqrtf((float)c);
        }
    }
    if (b == nb - 1 && threadIdx.x == 0) node_offs[n] = s1;
    __syncthreads();
    for (int i = s0 + (int)threadIdx.x; i < s1; i += 256) {
        unsigned int e = sd[i];
        int l = (int)(e >> 25);
        int p = s0 + atomicAdd(&cur[l], 1);
        src_sorted[p] = (int)(e & 0x1FFFFFFu);
    }
}

// One wave per dst node. 16 lanes x float4 cover the 64-float row; the 4
// lane-quarters process 4 edges concurrently. Optional per-edge scale
// edge_nrm[src] (layer 1 norm_src fold). Cross-quarter shfl_xor reduce.
__global__ __launch_bounds__(256) void gather_agg(const float* __restrict__ x,
        const float* __restrict__ edge_nrm,
        const int* __restrict__ srcs, const int* __restrict__ offs,
        const float* __restrict__ nrm, const float* __restrict__ bias,
        float* __restrict__ out, int n_nodes) {
    int wave = blockIdx.x * 4 + (threadIdx.x >> 6);
    if (wave >= n_nodes) return;
    int lane = threadIdx.x & 63;
    int g  = lane >> 4;
    int c4 = (lane & 15) * 4;
    int e0 = offs[wave];
    int e1 = offs[wave + 1];
    float ax = 0.0f, ay = 0.0f, az = 0.0f, aw = 0.0f;
    for (int base = e0; base < e1; base += 8) {
        #pragma unroll
        for (int u = 0; u < 2; ++u) {
            int ei = base + u * 4 + g;
            int idx = ei < e1 ? ei : e1 - 1;
            float msk = ei < e1 ? 1.0f : 0.0f;
            int s = srcs[idx];
            if (edge_nrm) msk *= edge_nrm[s];
            const float4 v = *(const float4*)(x + (size_t)s * 64 + c4);
            ax = fmaf(v.x, msk, ax);
            ay = fmaf(v.y, msk, ay);
            az = fmaf(v.z, msk, az);
            aw = fmaf(v.w, msk, aw);
        }
    }
    #pragma unroll
    for (int off = 16; off < 64; off <<= 1) {
        ax += __shfl_xor(ax, off, 64);
        ay += __shfl_xor(ay, off, 64);
        az += __shfl_xor(az, off, 64);
        aw += __shfl_xor(aw, off, 64);
    }
    if (g == 0) {
        float s = nrm[wave];
        float4 r;
        r.x = ax * s; r.y = ay * s; r.z = az * s; r.w = aw * s;
        if (bias) {
            const float4 b = *(const float4*)(bias + c4);
            r.x += b.x; r.y += b.y; r.z += b.z; r.w += b.w;
        }
        *(float4*)(out + (size_t)wave * 64 + c4) = r;
    }
}

// H1[n,128] = relu(A[n,64] @ W1[64,128] + b1) * norm_src[node]
__global__ __launch_bounds__(256) void gemm1(const float* __restrict__ A,
        const float* __restrict__ W1, const float* __restrict__ b1,
        const float* __restrict__ norm, float* __restrict__ H1, int n_nodes) {
    __shared__ float Ws[64 * 128];
    __shared__ float As[64 * 68];
    __shared__ float b1s[128];
    const int tid = threadIdx.x;
    for (int idx = tid; idx < 64 * 128; idx += 256) Ws[idx] = W1[idx];
    if (tid < 128) b1s[tid] = b1[tid];

    const int m0 = blockIdx.x * 64;
    const float4* Ag = (const float4*)(A + (size_t)m0 * 64);
    #pragma unroll
    for (int i = 0; i < 4; ++i) {
        int idx = tid + i * 256;
        int m = idx >> 4;
        int k4 = (idx & 15) * 4;
        float4 v = make_float4(0.f, 0.f, 0.f, 0.f);
        if (m0 + m < n_nodes) v = Ag[idx];
        *(float4*)(As + m * 68 + k4) = v;
    }
    __syncthreads();

    const int tx = tid & 15;
    const int ty = tid >> 4;
    float acc[4][8];
    #pragma unroll
    for (int i = 0; i < 4; ++i)
        #pragma unroll
        for (int j = 0; j < 8; ++j) acc[i][j] = 0.0f;

    const float* Ap = As + ty * 4 * 68;
    const float* Wp = Ws + tx * 8;
    for (int k = 0; k < 64; ++k) {
        float a0 = Ap[k];
        float a1 = Ap[68 + k];
        float a2 = Ap[136 + k];
        float a3 = Ap[204 + k];
        float w[8];
        #pragma unroll
        for (int j = 0; j < 8; ++j) w[j] = Wp[k * 128 + j];
        #pragma unroll
        for (int j = 0; j < 8; ++j) {
            acc[0][j] = fmaf(a0, w[j], acc[0][j]);
            acc[1][j] = fmaf(a1, w[j], acc[1][j]);
            acc[2][j] = fmaf(a2, w[j], acc[2][j]);
            acc[3][j] = fmaf(a3, w[j], acc[3][j]);
        }
    }

    #pragma unroll
    for (int i = 0; i < 4; ++i) {
        int node = m0 + ty * 4 + i;
        if (node < n_nodes) {
            float s = norm[node];
            float r[8];
            #pragma unroll
            for (int j = 0; j < 8; ++j) {
                float v = acc[i][j] + b1s[tx * 8 + j];
                v = v > 0.0f ? v : 0.0f;
                r[j] = v * s;
            }
            float* o = H1 + (size_t)node * 128 + tx * 8;
            *(float4*)(o)     = make_float4(r[0], r[1], r[2], r[3]);
            *(float4*)(o + 4) = make_float4(r[4], r[5], r[6], r[7]);
        }
    }
}

// Y2[n,64] = H1[n,128] @ W2[128,64]
__global__ __launch_bounds__(256) void gemm2(const float* __restrict__ H1,
        const float* __restrict__ W2, float* __restrict__ Y2, int n_nodes) {
    __shared__ float Ws[128 * 64];
    __shared__ float Hs[64 * 132];
    const int tid = threadIdx.x;
    for (int idx = tid; idx < 128 * 64; idx += 256) Ws[idx] = W2[idx];

    const int m0 = blockIdx.x * 64;
    const float4* Hg = (const float4*)(H1 + (size_t)m0 * 128);
    #pragma unroll
    for (int i = 0; i < 8; ++i) {
        int idx = tid + i * 256;
        int m = idx >> 5;
        int k4 = (idx & 31) * 4;
        float4 v = make_float4(0.f, 0.f, 0.f, 0.f);
        if (m0 + m < n_nodes) v = Hg[idx];
        *(float4*)(Hs + m * 132 + k4) = v;
    }
    __syncthreads();

    const int tx = tid & 15;
    const int ty = tid >> 4;
    float acc[4][4];
    #pragma unroll
    for (int i = 0; i < 4; ++i)
        #pragma unroll
        for (int j = 0; j < 4; ++j) acc[i][j] = 0.0f;

    const float* Ap = Hs + ty * 4 * 132;
    for (int k = 0; k < 128; ++k) {
        float a0 = Ap[k];
        float a1 = Ap[132 + k];
        float a2 = Ap[264 + k];
        float a3 = Ap[396 + k];
        const float4 w = *(const float4*)(Ws + k * 64 + tx * 4);
        acc[0][0] = fmaf(a0, w.x, acc[0][0]); acc[0][1] = fmaf(a0, w.y, acc[0][1]);
        acc[0][2] = fmaf(a0, w.z, acc[0][2]); acc[0][3] = fmaf(a0, w.w, acc[0][3]);
        acc[1][0] = fmaf(a1, w.x, acc[1][0]); acc[1][1] = fmaf(a1, w.y, acc[1][1]);
        acc[1][2] = fmaf(a1, w.z, acc[1][2]); acc[1][3] = fmaf(a1, w.w, acc[1][3]);
        acc[2][0] = fmaf(a2, w.x, acc[2][0]); acc[2][1] = fmaf(a2, w.y, acc[2][1]);
        acc[2][2] = fmaf(a2, w.z, acc[2][2]); acc[2][3] = fmaf(a2, w.w, acc[2][3]);
        acc[3][0] = fmaf(a3, w.x, acc[3][0]); acc[3][1] = fmaf(a3, w.y, acc[3][1]);
        acc[3][2] = fmaf(a3, w.z, acc[3][2]); acc[3][3] = fmaf(a3, w.w, acc[3][3]);
    }

    #pragma unroll
    for (int i = 0; i < 4; ++i) {
        int node = m0 + ty * 4 + i;
        if (node < n_nodes) {
            *(float4*)(Y2 + (size_t)node * 64 + tx * 4) =
                make_float4(acc[i][0], acc[i][1], acc[i][2], acc[i][3]);
        }
    }
}

extern "C" void kernel_launch(void* const* d_in, const int* in_sizes, int n_in,
                              void* d_out, int out_size, void* d_ws, size_t ws_size,
                              hipStream_t stream) {
    const float* h   = (const float*)d_in[0];
    const int*   src = (const int*)d_in[1];
    const int*   dst = (const int*)d_in[2];
    const float* W1  = (const float*)d_in[3];
    const float* b1  = (const float*)d_in[4];
    const float* W2  = (const float*)d_in[5];
    const float* b2  = (const float*)d_in[6];
    float* out = (float*)d_out;

    const int n_nodes = in_sizes[0] / 64;
    const int n_edges = in_sizes[1];
    const int nb = (n_nodes + 127) >> 7;

    float* ws = (float*)d_ws;
    float* agg1     = ws;                            // [n,64]; y2 alias later
    float* H1       = agg1 + (size_t)n_nodes * 64;   // [n,128]
    float* norm_src = H1 + (size_t)n_nodes * 128;    // [n]
    float* norm_dst = norm_src + n_nodes;            // [n]
    int* node_offs  = (int*)(norm_dst + n_nodes);    // [n+1]
    int* gcnt_s = node_offs + n_nodes + 1;           // [nb]
    int* gcnt_d = gcnt_s + nb;                       // [nb]
    int* offs_s = gcnt_d + nb;                       // [nb+1]
    int* offs_d = offs_s + nb + 1;                   // [nb+1]
    int* cur_s  = offs_d + nb + 1;                   // [nb]
    int* cur_d  = cur_s + nb;                        // [nb]
    int* src_sorted = cur_d + nb;                    // [E]
    unsigned int* sd = (unsigned int*)(src_sorted + n_edges);  // [E]
    unsigned char* ss = (unsigned char*)(sd + n_edges);        // [E] bytes
    float* y2 = agg1;  // alias: agg1 dead after gemm1

    hipMemsetAsync(gcnt_s, 0, 2 * (size_t)nb * sizeof(int), stream);

    bucket_hist<<<256, 256, 0, stream>>>(src, dst, gcnt_s, gcnt_d, n_edges, nb);
    scan2<<<2, 1024, 0, stream>>>(gcnt_s, offs_s, cur_s, gcnt_d, offs_d, cur_d, nb);
    bucket_place<<<256, 256, 0, stream>>>(src, dst, cur_s, cur_d, ss, sd, n_edges, nb);
    src_deg<<<nb, 256, 0, stream>>>(ss, offs_s, norm_src, n_nodes);
    bucket_sort<<<nb, 256, 0, stream>>>(sd, offs_d, node_offs, src_sorted,
                                        norm_dst, n_nodes, nb);

    int gb = (n_nodes + 3) / 4;
    gather_agg<<<gb, 256, 0, stream>>>(h, norm_src, src_sorted, node_offs,
                                       norm_dst, nullptr, agg1, n_nodes);

    int tb = (n_nodes + 63) / 64;
    gemm1<<<tb, 256, 0, stream>>>(agg1, W1, b1, norm_src, H1, n_nodes);
    gemm2<<<tb, 256, 0, stream>>>(H1, W2, y2, n_nodes);

    gather_agg<<<gb, 256, 0, stream>>>(y2, nullptr, src_sorted, node_offs,
                                       norm_dst, b2, out, n_nodes);
}

// Round 6
// 228.443 us; speedup vs baseline: 4.0837x; 1.0779x over previous
//
#include <hip/hip_runtime.h>

// F0=64, F1=128, F2=64. Two-level CSR build (buckets of 128 nodes, LDS
// histograms) + one-wave-per-node register gather over bf16 rows (f32 accum).
// Pipeline: bucket_hist -> scan2 -> bucket_place -> src_deg -> bucket_sort ->
//           scale_cast(x=bf16(h*norm_src)) -> gather1 -> gemm1 -> gemm2(bf16 out)
//           -> gather2(+b2, f32 out)

#define NBMAX 1024  // supports n up to 131072

__device__ inline unsigned short f2bf(float f) {
    unsigned int u = __float_as_uint(f);
    unsigned int r = (u + 0x7FFFu + ((u >> 16) & 1u)) >> 16;  // round-nearest-even
    return (unsigned short)r;
}
__device__ inline float bf2f(unsigned short h) {
    return __uint_as_float((unsigned int)h << 16);
}

__global__ __launch_bounds__(256) void bucket_hist(const int* __restrict__ src,
        const int* __restrict__ dst, int* __restrict__ gcnt_s, int* __restrict__ gcnt_d,
        int n_edges, int nb) {
    __shared__ int hs[NBMAX], hd[NBMAX];
    for (int i = threadIdx.x; i < nb; i += 256) { hs[i] = 0; hd[i] = 0; }
    __syncthreads();
    int chunk = (n_edges + gridDim.x - 1) / gridDim.x;
    int e0 = blockIdx.x * chunk;
    int e1 = e0 + chunk; if (e1 > n_edges) e1 = n_edges;
    for (int e = e0 + (int)threadIdx.x; e < e1; e += 256) {
        atomicAdd(&hs[src[e] >> 7], 1);
        atomicAdd(&hd[dst[e] >> 7], 1);
    }
    __syncthreads();
    for (int i = threadIdx.x; i < nb; i += 256) {
        if (hs[i]) atomicAdd(&gcnt_s[i], hs[i]);
        if (hd[i]) atomicAdd(&gcnt_d[i], hd[i]);
    }
}

// block 0 scans (c0->o0,u0), block 1 scans (c1->o1,u1).
__global__ __launch_bounds__(1024) void scan2(const int* __restrict__ c0,
        int* __restrict__ o0, int* __restrict__ u0,
        const int* __restrict__ c1, int* __restrict__ o1, int* __restrict__ u1, int n) {
    const int* cnt = blockIdx.x ? c1 : c0;
    int* offs = blockIdx.x ? o1 : o0;
    int* cur  = blockIdx.x ? u1 : u0;
    __shared__ int wsum[16];
    const int lane = threadIdx.x & 63;
    const int wid  = threadIdx.x >> 6;
    int carry = 0;
    for (int base = 0; base < n; base += 1024) {
        int i = base + (int)threadIdx.x;
        int v = (i < n) ? cnt[i] : 0;
        int incl = v;
        #pragma unroll
        for (int d = 1; d < 64; d <<= 1) {
            int t = __shfl_up(incl, d, 64);
            if (lane >= d) incl += t;
        }
        if (lane == 63) wsum[wid] = incl;
        __syncthreads();
        if (wid == 0) {
            int w = (lane < 16) ? wsum[lane] : 0;
            #pragma unroll
            for (int d = 1; d < 16; d <<= 1) {
                int t = __shfl_up(w, d, 64);
                if (lane >= d) w += t;
            }
            if (lane < 16) wsum[lane] = w;
        }
        __syncthreads();
        int wexcl = (wid == 0) ? 0 : wsum[wid - 1];
        int excl = carry + wexcl + (incl - v);
        if (i < n) { offs[i] = excl; cur[i] = excl; }
        int total = wsum[15];
        __syncthreads();
        carry += total;
    }
    if (threadIdx.x == 0) offs[n] = carry;
}

// Per-block LDS hist -> one reservation atomic per (block,bucket) -> LDS-cursor
// scatter. dst entry: (dst&127)<<25 | src. src entry: 1 byte local id.
__global__ __launch_bounds__(256) void bucket_place(const int* __restrict__ src,
        const int* __restrict__ dst, int* __restrict__ cur_s, int* __restrict__ cur_d,
        unsigned char* __restrict__ ss, unsigned int* __restrict__ sd,
        int n_edges, int nb) {
    __shared__ int hs[NBMAX], hd[NBMAX], bs[NBMAX], bd[NBMAX];
    for (int i = threadIdx.x; i < nb; i += 256) { hs[i] = 0; hd[i] = 0; }
    __syncthreads();
    int chunk = (n_edges + gridDim.x - 1) / gridDim.x;
    int e0 = blockIdx.x * chunk;
    int e1 = e0 + chunk; if (e1 > n_edges) e1 = n_edges;
    for (int e = e0 + (int)threadIdx.x; e < e1; e += 256) {
        atomicAdd(&hs[src[e] >> 7], 1);
        atomicAdd(&hd[dst[e] >> 7], 1);
    }
    __syncthreads();
    for (int i = threadIdx.x; i < nb; i += 256) {
        int v = hs[i]; bs[i] = v ? atomicAdd(&cur_s[i], v) : 0; hs[i] = 0;
        v = hd[i];     bd[i] = v ? atomicAdd(&cur_d[i], v) : 0; hd[i] = 0;
    }
    __syncthreads();
    for (int e = e0 + (int)threadIdx.x; e < e1; e += 256) {
        int s = src[e], d = dst[e];
        int b1 = s >> 7, b2 = d >> 7;
        int ps = bs[b1] + atomicAdd(&hs[b1], 1);
        ss[ps] = (unsigned char)(s & 127);
        int pd = bd[b2] + atomicAdd(&hd[b2], 1);
        sd[pd] = ((unsigned int)(d & 127) << 25) | (unsigned int)s;
    }
}

// One block per src-bucket: count occurrences -> norm_src.
__global__ __launch_bounds__(256) void src_deg(const unsigned char* __restrict__ ss,
        const int* __restrict__ offs_s, float* __restrict__ norm_src, int n) {
    __shared__ int cnt[128];
    if (threadIdx.x < 128) cnt[threadIdx.x] = 0;
    __syncthreads();
    int b = blockIdx.x;
    int s0 = offs_s[b], s1 = offs_s[b + 1];
    for (int i = s0 + (int)threadIdx.x; i < s1; i += 256)
        atomicAdd(&cnt[ss[i]], 1);
    __syncthreads();
    if (threadIdx.x < 128) {
        int node = b * 128 + (int)threadIdx.x;
        if (node < n) {
            int c = cnt[threadIdx.x]; if (c < 1) c = 1;
            norm_src[node] = 1.0f / sqrtf((float)c);
        }
    }
}

// One block per dst-bucket: 128-bin count -> scan -> per-node CSR offsets +
// LDS-cursor placement of full src ids. Also writes norm_dst.
__global__ __launch_bounds__(256) void bucket_sort(const unsigned int* __restrict__ sd,
        const int* __restrict__ offs_d, int* __restrict__ node_offs,
        int* __restrict__ src_sorted, float* __restrict__ norm_dst, int n, int nb) {
    __shared__ int cnt[128], cur[128];
    __shared__ int w0tot;
    const int b = blockIdx.x;
    const int s0 = offs_d[b], s1 = offs_d[b + 1];
    if (threadIdx.x < 128) cnt[threadIdx.x] = 0;
    __syncthreads();
    for (int i = s0 + (int)threadIdx.x; i < s1; i += 256)
        atomicAdd(&cnt[sd[i] >> 25], 1);
    __syncthreads();
    const int lane = threadIdx.x & 63;
    const int wid  = threadIdx.x >> 6;
    int v = (threadIdx.x < 128) ? cnt[threadIdx.x] : 0;
    int incl = v;
    #pragma unroll
    for (int d = 1; d < 64; d <<= 1) {
        int t = __shfl_up(incl, d, 64);
        if (lane >= d) incl += t;
    }
    if (threadIdx.x == 63) w0tot = incl;
    __syncthreads();
    if (threadIdx.x < 128) {
        int excl = incl - v + (wid == 1 ? w0tot : 0);
        cur[threadIdx.x] = excl;
        int node = b * 128 + (int)threadIdx.x;
        if (node < n) {
            node_offs[node] = s0 + excl;
            int c = v; if (c < 1) c = 1;
            norm_dst[node] = 1.0f / sqrtf((float)c);
        }
    }
    if (b == nb - 1 && threadIdx.x == 0) node_offs[n] = s1;
    __syncthreads();
    for (int i = s0 + (int)threadIdx.x; i < s1; i += 256) {
        unsigned int e = sd[i];
        int l = (int)(e >> 25);
        int p = s0 + atomicAdd(&cur[l], 1);
        src_sorted[p] = (int)(e & 0x1FFFFFFu);
    }
}

// xb = bf16(h * norm_src[node]); 16 float4 -> 16 ushort4 per node.
__global__ void scale_cast(const float4* __restrict__ h4, const float* __restrict__ norm,
                           ushort4* __restrict__ xb4, int n4) {
    int idx = blockIdx.x * blockDim.x + threadIdx.x;
    if (idx < n4) {
        float s = norm[idx >> 4];
        float4 v = h4[idx];
        ushort4 o;
        o.x = f2bf(v.x * s); o.y = f2bf(v.y * s);
        o.z = f2bf(v.z * s); o.w = f2bf(v.w * s);
        xb4[idx] = o;
    }
}

// One wave per dst node over bf16 rows (128 B). 16 lanes x bf16x4 cover the
// 64-wide row; 4 lane-quarters process 4 edges concurrently, unroll 2 -> 8 in
// flight. f32 accumulate, cross-quarter shfl_xor reduce, f32 row write.
__global__ __launch_bounds__(256) void gather_bf(const unsigned short* __restrict__ xb,
        const int* __restrict__ srcs, const int* __restrict__ offs,
        const float* __restrict__ nrm, const float* __restrict__ bias,
        float* __restrict__ out, int n_nodes) {
    int wave = blockIdx.x * 4 + (threadIdx.x >> 6);
    if (wave >= n_nodes) return;
    int lane = threadIdx.x & 63;
    int g  = lane >> 4;
    int c4 = (lane & 15) * 4;
    int e0 = offs[wave];
    int e1 = offs[wave + 1];
    float ax = 0.0f, ay = 0.0f, az = 0.0f, aw = 0.0f;
    for (int base = e0; base < e1; base += 8) {
        #pragma unroll
        for (int u = 0; u < 2; ++u) {
            int ei = base + u * 4 + g;
            int idx = ei < e1 ? ei : e1 - 1;
            float msk = ei < e1 ? 1.0f : 0.0f;
            int s = srcs[idx];
            const ushort4 v = *(const ushort4*)(xb + (size_t)s * 64 + c4);
            ax = fmaf(bf2f(v.x), msk, ax);
            ay = fmaf(bf2f(v.y), msk, ay);
            az = fmaf(bf2f(v.z), msk, az);
            aw = fmaf(bf2f(v.w), msk, aw);
        }
    }
    #pragma unroll
    for (int off = 16; off < 64; off <<= 1) {
        ax += __shfl_xor(ax, off, 64);
        ay += __shfl_xor(ay, off, 64);
        az += __shfl_xor(az, off, 64);
        aw += __shfl_xor(aw, off, 64);
    }
    if (g == 0) {
        float s = nrm[wave];
        float4 r;
        r.x = ax * s; r.y = ay * s; r.z = az * s; r.w = aw * s;
        if (bias) {
            const float4 b = *(const float4*)(bias + c4);
            r.x += b.x; r.y += b.y; r.z += b.z; r.w += b.w;
        }
        *(float4*)(out + (size_t)wave * 64 + c4) = r;
    }
}

// H1[n,128] = relu(A[n,64] @ W1[64,128] + b1) * norm_src[node]
__global__ __launch_bounds__(256) void gemm1(const float* __restrict__ A,
        const float* __restrict__ W1, const float* __restrict__ b1,
        const float* __restrict__ norm, float* __restrict__ H1, int n_nodes) {
    __shared__ float Ws[64 * 128];
    __shared__ float As[64 * 68];
    __shared__ float b1s[128];
    const int tid = threadIdx.x;
    for (int idx = tid; idx < 64 * 128; idx += 256) Ws[idx] = W1[idx];
    if (tid < 128) b1s[tid] = b1[tid];

    const int m0 = blockIdx.x * 64;
    const float4* Ag = (const float4*)(A + (size_t)m0 * 64);
    #pragma unroll
    for (int i = 0; i < 4; ++i) {
        int idx = tid + i * 256;
        int m = idx >> 4;
        int k4 = (idx & 15) * 4;
        float4 v = make_float4(0.f, 0.f, 0.f, 0.f);
        if (m0 + m < n_nodes) v = Ag[idx];
        *(float4*)(As + m * 68 + k4) = v;
    }
    __syncthreads();

    const int tx = tid & 15;
    const int ty = tid >> 4;
    float acc[4][8];
    #pragma unroll
    for (int i = 0; i < 4; ++i)
        #pragma unroll
        for (int j = 0; j < 8; ++j) acc[i][j] = 0.0f;

    const float* Ap = As + ty * 4 * 68;
    const float* Wp = Ws + tx * 8;
    for (int k = 0; k < 64; ++k) {
        float a0 = Ap[k];
        float a1 = Ap[68 + k];
        float a2 = Ap[136 + k];
        float a3 = Ap[204 + k];
        float w[8];
        #pragma unroll
        for (int j = 0; j < 8; ++j) w[j] = Wp[k * 128 + j];
        #pragma unroll
        for (int j = 0; j < 8; ++j) {
            acc[0][j] = fmaf(a0, w[j], acc[0][j]);
            acc[1][j] = fmaf(a1, w[j], acc[1][j]);
            acc[2][j] = fmaf(a2, w[j], acc[2][j]);
            acc[3][j] = fmaf(a3, w[j], acc[3][j]);
        }
    }

    #pragma unroll
    for (int i = 0; i < 4; ++i) {
        int node = m0 + ty * 4 + i;
        if (node < n_nodes) {
            float s = norm[node];
            float r[8];
            #pragma unroll
            for (int j = 0; j < 8; ++j) {
                float v = acc[i][j] + b1s[tx * 8 + j];
                v = v > 0.0f ? v : 0.0f;
                r[j] = v * s;
            }
            float* o = H1 + (size_t)node * 128 + tx * 8;
            *(float4*)(o)     = make_float4(r[0], r[1], r[2], r[3]);
            *(float4*)(o + 4) = make_float4(r[4], r[5], r[6], r[7]);
        }
    }
}

// Y2b[n,64] = bf16(H1[n,128] @ W2[128,64])
__global__ __launch_bounds__(256) void gemm2b(const float* __restrict__ H1,
        const float* __restrict__ W2, unsigned short* __restrict__ Y2b, int n_nodes) {
    __shared__ float Ws[128 * 64];
    __shared__ float Hs[64 * 132];
    const int tid = threadIdx.x;
    for (int idx = tid; idx < 128 * 64; idx += 256) Ws[idx] = W2[idx];

    const int m0 = blockIdx.x * 64;
    const float4* Hg = (const float4*)(H1 + (size_t)m0 * 128);
    #pragma unroll
    for (int i = 0; i < 8; ++i) {
        int idx = tid + i * 256;
        int m = idx >> 5;
        int k4 = (idx & 31) * 4;
        float4 v = make_float4(0.f, 0.f, 0.f, 0.f);
        if (m0 + m < n_nodes) v = Hg[idx];
        *(float4*)(Hs + m * 132 + k4) = v;
    }
    __syncthreads();

    const int tx = tid & 15;
    const int ty = tid >> 4;
    float acc[4][4];
    #pragma unroll
    for (int i = 0; i < 4; ++i)
        #pragma unroll
        for (int j = 0; j < 4; ++j) acc[i][j] = 0.0f;

    const float* Ap = Hs + ty * 4 * 132;
    for (int k = 0; k < 128; ++k) {
        float a0 = Ap[k];
        float a1 = Ap[132 + k];
        float a2 = Ap[264 + k];
        float a3 = Ap[396 + k];
        const float4 w = *(const float4*)(Ws + k * 64 + tx * 4);
        acc[0][0] = fmaf(a0, w.x, acc[0][0]); acc[0][1] = fmaf(a0, w.y, acc[0][1]);
        acc[0][2] = fmaf(a0, w.z, acc[0][2]); acc[0][3] = fmaf(a0, w.w, acc[0][3]);
        acc[1][0] = fmaf(a1, w.x, acc[1][0]); acc[1][1] = fmaf(a1, w.y, acc[1][1]);
        acc[1][2] = fmaf(a1, w.z, acc[1][2]); acc[1][3] = fmaf(a1, w.w, acc[1][3]);
        acc[2][0] = fmaf(a2, w.x, acc[2][0]); acc[2][1] = fmaf(a2, w.y, acc[2][1]);
        acc[2][2] = fmaf(a2, w.z, acc[2][2]); acc[2][3] = fmaf(a2, w.w, acc[2][3]);
        acc[3][0] = fmaf(a3, w.x, acc[3][0]); acc[3][1] = fmaf(a3, w.y, acc[3][1]);
        acc[3][2] = fmaf(a3, w.z, acc[3][2]); acc[3][3] = fmaf(a3, w.w, acc[3][3]);
    }

    #pragma unroll
    for (int i = 0; i < 4; ++i) {
        int node = m0 + ty * 4 + i;
        if (node < n_nodes) {
            ushort4 o;
            o.x = f2bf(acc[i][0]); o.y = f2bf(acc[i][1]);
            o.z = f2bf(acc[i][2]); o.w = f2bf(acc[i][3]);
            *(ushort4*)(Y2b + (size_t)node * 64 + tx * 4) = o;
        }
    }
}

extern "C" void kernel_launch(void* const* d_in, const int* in_sizes, int n_in,
                              void* d_out, int out_size, void* d_ws, size_t ws_size,
                              hipStream_t stream) {
    const float* h   = (const float*)d_in[0];
    const int*   src = (const int*)d_in[1];
    const int*   dst = (const int*)d_in[2];
    const float* W1  = (const float*)d_in[3];
    const float* b1  = (const float*)d_in[4];
    const float* W2  = (const float*)d_in[5];
    const float* b2  = (const float*)d_in[6];
    float* out = (float*)d_out;

    const int n_nodes = in_sizes[0] / 64;
    const int n_edges = in_sizes[1];
    const int nb = (n_nodes + 127) >> 7;

    float* ws = (float*)d_ws;
    float* agg1     = ws;                            // [n,64] f32
    float* H1       = agg1 + (size_t)n_nodes * 64;   // [n,128] f32
    float* norm_src = H1 + (size_t)n_nodes * 128;    // [n]
    float* norm_dst = norm_src + n_nodes;            // [n]
    int* node_offs  = (int*)(norm_dst + n_nodes);    // [n+1]
    int* gcnt_s = node_offs + n_nodes + 1;           // [nb]
    int* gcnt_d = gcnt_s + nb;                       // [nb]
    int* offs_s = gcnt_d + nb;                       // [nb+1]
    int* offs_d = offs_s + nb + 1;                   // [nb+1]
    int* cur_s  = offs_d + nb + 1;                   // [nb]
    int* cur_d  = cur_s + nb;                        // [nb]
    int* src_sorted = cur_d + nb;                    // [E]
    unsigned int* sd = (unsigned int*)(src_sorted + n_edges);  // [E]
    unsigned short* xb  = (unsigned short*)(sd + n_edges);     // [n,64] bf16
    unsigned short* y2b = xb + (size_t)n_nodes * 64;           // [n,64] bf16
    unsigned char* ss = (unsigned char*)(y2b + (size_t)n_nodes * 64);  // [E] bytes

    hipMemsetAsync(gcnt_s, 0, 2 * (size_t)nb * sizeof(int), stream);

    bucket_hist<<<256, 256, 0, stream>>>(src, dst, gcnt_s, gcnt_d, n_edges, nb);
    scan2<<<2, 1024, 0, stream>>>(gcnt_s, offs_s, cur_s, gcnt_d, offs_d, cur_d, nb);
    bucket_place<<<256, 256, 0, stream>>>(src, dst, cur_s, cur_d, ss, sd, n_edges, nb);
    src_deg<<<nb, 256, 0, stream>>>(ss, offs_s, norm_src, n_nodes);
    bucket_sort<<<nb, 256, 0, stream>>>(sd, offs_d, node_offs, src_sorted,
                                        norm_dst, n_nodes, nb);

    int n4 = n_nodes * 16;
    scale_cast<<<(n4 + 255) / 256, 256, 0, stream>>>((const float4*)h, norm_src,
                                                     (ushort4*)xb, n4);

    int gb = (n_nodes + 3) / 4;
    gather_bf<<<gb, 256, 0, stream>>>(xb, src_sorted, node_offs, norm_dst,
                                      nullptr, agg1, n_nodes);

    int tb = (n_nodes + 63) / 64;
    gemm1<<<tb, 256, 0, stream>>>(agg1, W1, b1, norm_src, H1, n_nodes);
    gemm2b<<<tb, 256, 0, stream>>>(H1, W2, y2b, n_nodes);

    gather_bf<<<gb, 256, 0, stream>>>(y2b, src_sorted, node_offs, norm_dst,
                                      b2, out, n_nodes);
}